// Round 7
// baseline (668.883 us; speedup 1.0000x reference)
//
#include <hip/hip_runtime.h>
#include <math.h>

// Problem constants (MambaBlock): B=2, L=4096, D=2048, H=32, DS=64, K=4
#define BB   2
#define LL   4096
#define DD   2048
#define HH   32
#define DSS  64
#define MM   (BB * LL)        // 8192 rows
#define N3   (3 * HH * DSS)   // 6144
#define NCH  64               // scan chunks
#define CLN  64               // steps per chunk (NCH*CLN == LL)
#define EPSF 1e-6f
#define GP_NB (DD / 128)      // 16 gate n-blocks
#define PP_NB (N3 / 128)      // 48 proj n-blocks

typedef unsigned short bf16;  // raw bf16 bits — we own the representation
typedef __attribute__((ext_vector_type(8))) short bf16x8;  // MFMA A/B frag (4 VGPRs)
typedef __attribute__((ext_vector_type(4))) float f32x4;   // MFMA C/D frag

__device__ __forceinline__ float bf2f(bf16 u) {
    union { unsigned int i; float f; } v;
    v.i = ((unsigned int)u) << 16;
    return v.f;
}
__device__ __forceinline__ bf16 f2bf(float f) {
    union { float f; unsigned int u; } v;
    v.f = f;
    unsigned int r = (v.u >> 16) & 1u;       // round to nearest even
    return (bf16)((v.u + 0x7fffu + r) >> 16);
}
__device__ __forceinline__ float sigmoidf_(float v) {
    return 1.0f / (1.0f + __expf(-v));
}
__device__ __forceinline__ void gload16(const void* g, void* l) {
    __builtin_amdgcn_global_load_lds(
        (const __attribute__((address_space(1))) void*)g,
        (__attribute__((address_space(3))) void*)l, 16, 0, 0);
}

// ------------------- dispatch 1: RMSNorm + all 3 weight transposes ----------
// blocks [0, MM): rms rows. Then gp (2048), op (2048), pp (6144) transpose
// tiles of 32n x 64k, fp32 -> bf16, ushort4 stores.
#define TR_GP 2048
#define TR_OP 2048
#define TR_PP 6144
__global__ __launch_bounds__(256) void rms_transpose(const float* __restrict__ x,
                                                     const float* __restrict__ w,
                                                     bf16* __restrict__ xn,
                                                     const float* __restrict__ gp_w,
                                                     const float* __restrict__ op_w,
                                                     const float* __restrict__ pp_w,
                                                     bf16* __restrict__ gp_wT,
                                                     bf16* __restrict__ op_wT,
                                                     bf16* __restrict__ pp_wT) {
    __shared__ float sh[64 * 33];
    int t = threadIdx.x;
    if (blockIdx.x < MM) {
        // ---- RMSNorm row ----
        int row = blockIdx.x;
        const float4* x4 = (const float4*)(x + (size_t)row * DD);
        ushort4* o4 = (ushort4*)(xn + (size_t)row * DD);
        const float4* w4 = (const float4*)w;
        float4 v0 = x4[t], v1 = x4[t + 256];
        float ss = v0.x * v0.x + v0.y * v0.y + v0.z * v0.z + v0.w * v0.w +
                   v1.x * v1.x + v1.y * v1.y + v1.z * v1.z + v1.w * v1.w;
#pragma unroll
        for (int off = 32; off >= 1; off >>= 1) ss += __shfl_down(ss, off, 64);
        if ((t & 63) == 0) sh[t >> 6] = ss;
        __syncthreads();
        float tot = sh[0] + sh[1] + sh[2] + sh[3];
        float inv = 1.0f / sqrtf(tot * (1.0f / DD) + EPSF);
        float4 wa = w4[t], wb = w4[t + 256];
        ushort4 r0, r1;
        r0.x = f2bf(v0.x * inv * wa.x); r0.y = f2bf(v0.y * inv * wa.y);
        r0.z = f2bf(v0.z * inv * wa.z); r0.w = f2bf(v0.w * inv * wa.w);
        r1.x = f2bf(v1.x * inv * wb.x); r1.y = f2bf(v1.y * inv * wb.y);
        r1.z = f2bf(v1.z * inv * wb.z); r1.w = f2bf(v1.w * inv * wb.w);
        o4[t] = r0; o4[t + 256] = r1;
    } else {
        // ---- transpose tile: 32 n x 64 k ----
        int id = blockIdx.x - MM;
        const float* W; bf16* WT; int Ndim, nblk, kblk;
        if (id < TR_GP)               { W = gp_w; WT = gp_wT; Ndim = DD;
                                        nblk = id & 63; kblk = id >> 6; }
        else if (id < TR_GP + TR_OP)  { id -= TR_GP; W = op_w; WT = op_wT; Ndim = DD;
                                        nblk = id & 63; kblk = id >> 6; }
        else                          { id -= TR_GP + TR_OP; W = pp_w; WT = pp_wT; Ndim = N3;
                                        nblk = id % 192; kblk = id / 192; }
        int n0 = nblk << 5, k0 = kblk << 6;
        float (*tl)[33] = (float (*)[33])sh;
        int tn = t & 31, tk = t >> 5;            // load: 8 k-rows per pass
#pragma unroll
        for (int i = 0; i < 64; i += 8)
            tl[tk + i][tn] = W[(size_t)(k0 + tk + i) * Ndim + n0 + tn];
        __syncthreads();
        int kq = (t & 15) << 2, tn2 = t >> 4;    // store: ushort4 along k
#pragma unroll
        for (int i = 0; i < 32; i += 16) {
            int n = tn2 + i;
            ushort4 v = { f2bf(tl[kq + 0][n]), f2bf(tl[kq + 1][n]),
                          f2bf(tl[kq + 2][n]), f2bf(tl[kq + 3][n]) };
            *(ushort4*)&WT[(size_t)(n0 + n) * DD + k0 + kq] = v;
        }
    }
}

// ---------------------------- MFMA bf16 GEMM core (BK=64, XOR-swizzled LDS) --
// One 128x128 tile of out = A @ Bt^T + bias. EPI: 1 sigmoid, 2 +add. K = DD.
template <int EPI, typename OutT>
__device__ __forceinline__ void gemm_tile(const bf16* __restrict__ A,
                                          const bf16* __restrict__ Bt,
                                          const float* __restrict__ bias,
                                          const float* __restrict__ add,
                                          OutT* __restrict__ out,
                                          int Ndim, int m0, int n0,
                                          bf16* As, bf16* Bs) {
    const int tid  = threadIdx.x;
    const int wave = tid >> 6;
    const int lane = tid & 63;
    const int sr = lane >> 3;
    const int gcol = ((lane & 7) ^ sr) << 3;
    const bf16* gA[4];
    const bf16* gB[4];
    bf16* lA[4];
    bf16* lB[4];
#pragma unroll
    for (int p = 0; p < 4; ++p) {
        int c = wave * 4 + p;
        gA[p] = A  + (size_t)(m0 + c * 8 + sr) * DD + gcol;
        gB[p] = Bt + (size_t)(n0 + c * 8 + sr) * DD + gcol;
        lA[p] = As + c * 512 + lane * 8;
        lB[p] = Bs + c * 512 + lane * 8;
    }
    const int wm = (wave >> 1) << 6;
    const int wn = (wave & 1) << 6;
    const int fr = lane & 15;
    const int kg = lane >> 4;
    const int f7 = fr & 7;

    f32x4 acc[4][4] = {};
    for (int k0 = 0; k0 < DD; k0 += 64) {
        __syncthreads();
#pragma unroll
        for (int p = 0; p < 4; ++p) {
            gload16(gA[p] + k0, lA[p]);
            gload16(gB[p] + k0, lB[p]);
        }
        __syncthreads();
#pragma unroll
        for (int ks = 0; ks < 2; ++ks) {
            bf16x8 af[4], bf_[4];
#pragma unroll
            for (int i = 0; i < 4; ++i) {
                int gq = (((ks << 2) | kg) ^ f7) << 3;
                af[i]  = *(const bf16x8*)&As[(wm + i * 16 + fr) * 64 + gq];
                bf_[i] = *(const bf16x8*)&Bs[(wn + i * 16 + fr) * 64 + gq];
            }
#pragma unroll
            for (int i = 0; i < 4; ++i)
#pragma unroll
                for (int j = 0; j < 4; ++j)
                    acc[i][j] = __builtin_amdgcn_mfma_f32_16x16x32_bf16(
                        af[i], bf_[j], acc[i][j], 0, 0, 0);
        }
    }
    const int baseRow = m0 + wm + kg * 4;
    const int baseCol = n0 + wn + fr;
#pragma unroll
    for (int i = 0; i < 4; ++i) {
#pragma unroll
        for (int r = 0; r < 4; ++r) {
            int m = baseRow + i * 16 + r;
            size_t rowoff = (size_t)m * Ndim + baseCol;
#pragma unroll
            for (int j = 0; j < 4; ++j) {
                float v = acc[i][j][r] + bias[baseCol + j * 16];
                if (EPI == 1) v = sigmoidf_(v);
                if (EPI == 2) v += add[rowoff + j * 16];
                if constexpr (sizeof(OutT) == 4)
                    ((float*)out)[rowoff + j * 16] = v;
                else
                    ((bf16*)out)[rowoff + j * 16] = f2bf(v);
            }
        }
    }
}

// Proj-GEMM tile with plane-scatter epilogue: col = h*192 + jj*64 + s
// -> plane jj at [m*2048 + h*64 + s].
__device__ __forceinline__ void gemm_tile_proj(const bf16* __restrict__ A,
                                               const bf16* __restrict__ Bt,
                                               const float* __restrict__ bias,
                                               bf16* __restrict__ dp,
                                               bf16* __restrict__ Bp,
                                               bf16* __restrict__ Cp,
                                               int m0, int n0,
                                               bf16* As, bf16* Bs) {
    const int tid  = threadIdx.x;
    const int wave = tid >> 6;
    const int lane = tid & 63;
    const int sr = lane >> 3;
    const int gcol = ((lane & 7) ^ sr) << 3;
    const bf16* gA[4];
    const bf16* gB[4];
    bf16* lA[4];
    bf16* lB[4];
#pragma unroll
    for (int p = 0; p < 4; ++p) {
        int c = wave * 4 + p;
        gA[p] = A  + (size_t)(m0 + c * 8 + sr) * DD + gcol;
        gB[p] = Bt + (size_t)(n0 + c * 8 + sr) * DD + gcol;
        lA[p] = As + c * 512 + lane * 8;
        lB[p] = Bs + c * 512 + lane * 8;
    }
    const int wm = (wave >> 1) << 6;
    const int wn = (wave & 1) << 6;
    const int fr = lane & 15;
    const int kg = lane >> 4;
    const int f7 = fr & 7;

    f32x4 acc[4][4] = {};
    for (int k0 = 0; k0 < DD; k0 += 64) {
        __syncthreads();
#pragma unroll
        for (int p = 0; p < 4; ++p) {
            gload16(gA[p] + k0, lA[p]);
            gload16(gB[p] + k0, lB[p]);
        }
        __syncthreads();
#pragma unroll
        for (int ks = 0; ks < 2; ++ks) {
            bf16x8 af[4], bf_[4];
#pragma unroll
            for (int i = 0; i < 4; ++i) {
                int gq = (((ks << 2) | kg) ^ f7) << 3;
                af[i]  = *(const bf16x8*)&As[(wm + i * 16 + fr) * 64 + gq];
                bf_[i] = *(const bf16x8*)&Bs[(wn + i * 16 + fr) * 64 + gq];
            }
#pragma unroll
            for (int i = 0; i < 4; ++i)
#pragma unroll
                for (int j = 0; j < 4; ++j)
                    acc[i][j] = __builtin_amdgcn_mfma_f32_16x16x32_bf16(
                        af[i], bf_[j], acc[i][j], 0, 0, 0);
        }
    }
    const int baseRow = m0 + wm + kg * 4;
    const int baseCol = n0 + wn + fr;
    bf16* pl[4]; int po[4]; float bi[4];
#pragma unroll
    for (int j = 0; j < 4; ++j) {
        int col = baseCol + j * 16;
        int h = col / 192;
        int rr = col - h * 192;
        int jj = rr >> 6;
        int s = rr & 63;
        pl[j] = (jj == 0) ? dp : (jj == 1 ? Bp : Cp);
        po[j] = h * DSS + s;
        bi[j] = bias[col];
    }
#pragma unroll
    for (int i = 0; i < 4; ++i) {
#pragma unroll
        for (int r = 0; r < 4; ++r) {
            int m = baseRow + i * 16 + r;
#pragma unroll
            for (int j = 0; j < 4; ++j)
                pl[j][(size_t)m * DD + po[j]] = f2bf(acc[i][j][r] + bi[j]);
        }
    }
}

// ------------------- dispatch 2: proj GEMM (plane out) + conv+SiLU ----------
#define CONV_LC 16
#define CONV_NB 1024          // (LL/CONV_LC=256) * (DD/1024=2) * BB
__global__ __launch_bounds__(256) void proj_conv(const bf16* __restrict__ xn,
                                                 const bf16* __restrict__ pp_wT,
                                                 const float* __restrict__ pp_b,
                                                 bf16* __restrict__ dp,
                                                 bf16* __restrict__ Bp,
                                                 bf16* __restrict__ Cp,
                                                 const float* __restrict__ cw,
                                                 const float* __restrict__ cb,
                                                 bf16* __restrict__ xc) {
    __shared__ __align__(16) bf16 As[128 * 64];
    __shared__ __align__(16) bf16 Bs[128 * 64];
    int bid = blockIdx.x;
    if (bid < PP_NB * (MM / 128)) {
        int nblk = bid % PP_NB, mblk = bid / PP_NB;
        gemm_tile_proj(xn, pp_wT, pp_b, dp, Bp, Cp, mblk << 7, nblk << 7, As, Bs);
        return;
    }
    // ---- conv + SiLU (sliding window) ----
    int cid = bid - PP_NB * (MM / 128);
    int b = cid >> 9;
    int rem = cid & 511;
    int l0 = (rem & 255) * CONV_LC;
    int d0 = (rem >> 8) * 1024 + threadIdx.x * 4;
    float4 w[4];
    float bias[4];
#pragma unroll
    for (int j = 0; j < 4; ++j) {
        w[j] = ((const float4*)cw)[d0 + j];
        bias[j] = cb[d0 + j];
    }
    float win[3][4];
#pragma unroll
    for (int k = 0; k < 3; ++k) {
        int l = l0 - 3 + k;
        if (l >= 0) {
            ushort4 v = *(const ushort4*)&xn[((size_t)b * LL + l) * DD + d0];
            win[k][0] = bf2f(v.x); win[k][1] = bf2f(v.y);
            win[k][2] = bf2f(v.z); win[k][3] = bf2f(v.w);
        } else {
            win[k][0] = win[k][1] = win[k][2] = win[k][3] = 0.0f;
        }
    }
    size_t off = ((size_t)b * LL + l0) * DD + d0;
#pragma unroll 4
    for (int i = 0; i < CONV_LC; ++i) {
        ushort4 v = *(const ushort4*)&xn[off];
        float cur[4] = {bf2f(v.x), bf2f(v.y), bf2f(v.z), bf2f(v.w)};
        ushort4 o;
#pragma unroll
        for (int j = 0; j < 4; ++j) {
            float acc = bias[j] + win[0][j] * w[j].x + win[1][j] * w[j].y +
                        win[2][j] * w[j].z + cur[j] * w[j].w;
            float s = acc * sigmoidf_(acc);
            ((unsigned short*)&o)[j] = f2bf(s);
        }
        *(ushort4*)&xc[off] = o;
#pragma unroll
        for (int j = 0; j < 4; ++j) {
            win[0][j] = win[1][j]; win[1][j] = win[2][j]; win[2][j] = cur[j];
        }
        off += DD;
    }
}

// ------------------- dispatch 3: gate GEMM + scan phase 1 -------------------
#define SC1_NB (NCH * (HH / 8) * BB)   // 512
__global__ __launch_bounds__(256) void gate_scan1(const bf16* __restrict__ xc,
                                                  const bf16* __restrict__ gp_wT,
                                                  const float* __restrict__ gp_b,
                                                  bf16* __restrict__ gate,
                                                  const bf16* __restrict__ dp,
                                                  const bf16* __restrict__ Bpl,
                                                  float* __restrict__ cA,
                                                  float* __restrict__ cB) {
    __shared__ __align__(16) bf16 As[128 * 64];
    __shared__ __align__(16) bf16 Bs[128 * 64];
    int bid = blockIdx.x;
    if (bid < GP_NB * (MM / 128)) {
        gemm_tile<1, bf16>(xc, gp_wT, gp_b, nullptr, gate, DD,
                           (bid / GP_NB) << 7, (bid % GP_NB) << 7, As, Bs);
        return;
    }
    // ---- scan phase 1: per-chunk affine (a,b); 8 h's/block, 2 s/lane ----
    int sid = bid - GP_NB * (MM / 128);
    int c = sid & 63;
    int rem = sid >> 6;
    int hg = rem & 3, b = rem >> 2;
    int t = threadIdx.x;
    int h = hg * 8 + (t >> 5);
    int so = (t & 31) * 2;
    size_t base = ((size_t)(b * LL + c * CLN)) * DD + h * DSS + so;
    float a0 = 1.0f, b0 = 0.0f, a1 = 1.0f, b1 = 0.0f;
#pragma unroll 8
    for (int i = 0; i < CLN; ++i) {
        ushort2 dv = *(const ushort2*)&dp[base];
        ushort2 bv = *(const ushort2*)&Bpl[base];
        float d0 = sigmoidf_(bf2f(dv.x));
        float d1 = sigmoidf_(bf2f(dv.y));
        a0 *= d0; b0 = d0 * b0 + bf2f(bv.x);
        a1 *= d1; b1 = d1 * b1 + bf2f(bv.y);
        base += DD;
    }
    int idx = ((b * HH + h) * NCH + c) * DSS + so;
    *(float2*)&cA[idx] = make_float2(a0, a1);
    *(float2*)&cB[idx] = make_float2(b0, b1);
}

// ------------------- dispatch 4: scan phase 3 (prefix + replay + mix) -------
__global__ __launch_bounds__(256) void scan_phase3(const bf16* __restrict__ dp,
                                                   const bf16* __restrict__ Bpl,
                                                   const bf16* __restrict__ Cp,
                                                   const float* __restrict__ cA,
                                                   const float* __restrict__ cB,
                                                   const float* __restrict__ state,
                                                   const bf16* __restrict__ gate,
                                                   const bf16* __restrict__ xn,
                                                   bf16* __restrict__ mixed,
                                                   float* __restrict__ hlast) {
    int c = blockIdx.x, b = blockIdx.z;
    int t = threadIdx.x;
    int h = blockIdx.y * 8 + (t >> 5);
    int so = (t & 31) * 2;
    float2 hp = *(const float2*)&state[(b * HH + h) * DSS + so];
    int cbase = ((b * HH + h) * NCH) * DSS + so;
    for (int cc = 0; cc < c; ++cc) {
        float2 a = *(const float2*)&cA[cbase + cc * DSS];
        float2 bb = *(const float2*)&cB[cbase + cc * DSS];
        hp.x = a.x * hp.x + bb.x;
        hp.y = a.y * hp.y + bb.y;
    }
    size_t grow = ((size_t)(b * LL + c * CLN)) * DD + h * DSS + so;
#pragma unroll 4
    for (int i = 0; i < CLN; ++i) {
        ushort2 dv = *(const ushort2*)&dp[grow];
        ushort2 bv = *(const ushort2*)&Bpl[grow];
        ushort2 cv = *(const ushort2*)&Cp[grow];
        ushort2 gv = *(const ushort2*)&gate[grow];
        ushort2 xv = *(const ushort2*)&xn[grow];
        float d0 = sigmoidf_(bf2f(dv.x));
        float d1 = sigmoidf_(bf2f(dv.y));
        hp.x = d0 * hp.x + bf2f(bv.x);
        hp.y = d1 * hp.y + bf2f(bv.y);
        float g0 = bf2f(gv.x), g1 = bf2f(gv.y);
        float m0 = g0 * (bf2f(cv.x) * hp.x) + (1.0f - g0) * bf2f(xv.x);
        float m1 = g1 * (bf2f(cv.y) * hp.y) + (1.0f - g1) * bf2f(xv.y);
        ushort2 o = { f2bf(m0), f2bf(m1) };
        *(ushort2*)&mixed[grow] = o;
        grow += DD;
    }
    if (c == NCH - 1)
        *(float2*)&hlast[(b * HH + h) * DSS + so] = hp;
}

// ------------------- dispatch 5: out GEMM -----------------------------------
__global__ __launch_bounds__(256) void gemm_out(const bf16* __restrict__ mixed,
                                                const bf16* __restrict__ op_wT,
                                                const float* __restrict__ op_b,
                                                const float* __restrict__ x,
                                                float* __restrict__ y) {
    __shared__ __align__(16) bf16 As[128 * 64];
    __shared__ __align__(16) bf16 Bs[128 * 64];
    gemm_tile<2, float>(mixed, op_wT, op_b, x, y, DD,
                        blockIdx.y << 7, blockIdx.x << 7, As, Bs);
}

// ---------------------------------------------------------------------------
extern "C" void kernel_launch(void* const* d_in, const int* in_sizes, int n_in,
                              void* d_out, int out_size, void* d_ws, size_t ws_size,
                              hipStream_t stream) {
    const float* x      = (const float*)d_in[0];
    const float* state  = (const float*)d_in[1];
    const float* norm_w = (const float*)d_in[2];
    const float* conv_w = (const float*)d_in[3];
    const float* conv_b = (const float*)d_in[4];
    const float* pp_w   = (const float*)d_in[5];
    const float* pp_b   = (const float*)d_in[6];
    const float* gp_w   = (const float*)d_in[7];
    const float* gp_b   = (const float*)d_in[8];
    const float* op_w   = (const float*)d_in[9];
    const float* op_b   = (const float*)d_in[10];

    float* y     = (float*)d_out;                 // M*D floats (64 MB)
    float* hlast = y + (size_t)MM * DD;           // B*H*DS floats

    // ws: xn 32MB | xcbuf 32MB (xc -> mixed) | dp 32MB | Bp 32MB | Cp 32MB |
    //     cA,cB 2MB | gp_wT 8MB | op_wT 8MB                   total ~178MB
    // d_out y region (64MB): gate bf16 [0,32MB) | pp_wT bf16 [32,56MB)
    //   — both dead before gemm_out overwrites y with fp32 output.
    const size_t BHND = (size_t)BB * HH * NCH * DSS;
    char* ws = (char*)d_ws;
    bf16* xn    = (bf16*)ws;
    bf16* xcbuf = xn + (size_t)MM * DD;
    bf16* dp    = xcbuf + (size_t)MM * DD;
    bf16* Bp    = dp + (size_t)MM * DD;
    bf16* Cp    = Bp + (size_t)MM * DD;
    float* cA   = (float*)(Cp + (size_t)MM * DD);
    float* cB   = cA + BHND;
    bf16* gp_wT = (bf16*)(cB + BHND);
    bf16* op_wT = gp_wT + (size_t)DD * DD;
    bf16* gate  = (bf16*)y;                       // 32MB
    bf16* pp_wT = gate + (size_t)MM * DD;         // 24MB, in upper half of y
    bf16* mixed = xcbuf;

    // 1. RMSNorm + weight transposes
    rms_transpose<<<MM + TR_GP + TR_OP + TR_PP, 256, 0, stream>>>(
        x, norm_w, xn, gp_w, op_w, pp_w, gp_wT, op_wT, pp_wT);
    // 2. proj GEMM (plane outputs) + conv/SiLU (independent, overlapped)
    proj_conv<<<PP_NB * (MM / 128) + CONV_NB, 256, 0, stream>>>(
        xn, pp_wT, pp_b, dp, Bp, Cp, conv_w, conv_b, xcbuf);
    // 3. gate GEMM + scan phase1 (independent, overlapped)
    gate_scan1<<<GP_NB * (MM / 128) + SC1_NB, 256, 0, stream>>>(
        xcbuf, gp_wT, gp_b, gate, dp, Bp, cA, cB);
    // 4. scan phase 3: prefix + replay + mix (+ h_last)
    scan_phase3<<<dim3(NCH, HH / 8, BB), 256, 0, stream>>>(
        dp, Bp, Cp, cA, cB, state, gate, xn, mixed, hlast);
    // 5. y = mixed @ op_w + op_b + x
    gemm_out<<<dim3(GP_NB, MM / 128), 256, 0, stream>>>(mixed, op_wT, op_b, x, y);
}